// Round 10
// baseline (54.155 us; speedup 1.0000x reference)
//
#include <hip/hip_runtime.h>
#include <math.h>

#define BB 4
#define NN 1024
#define FF 128
#define DD 128
#define FOBS 32

typedef __attribute__((ext_vector_type(8))) short bfrag;   // 8 bf16 = 4 VGPR
typedef __attribute__((ext_vector_type(4))) float ffrag;   // 4 f32 acc
typedef __attribute__((ext_vector_type(4))) unsigned short us4;

#define NTRI 136                                  // 16*17/2 upper-tri 64x64 tiles

__device__ __forceinline__ unsigned short f2bf(float x) {
    unsigned u = __builtin_bit_cast(unsigned, x);
    u += 0x7fffu + ((u >> 16) & 1u);              // RNE
    return (unsigned short)(u >> 16);
}
__device__ __forceinline__ float bf2f(unsigned short s) {
    unsigned u = (unsigned)s << 16;
    return __builtin_bit_cast(float, u);
}
__device__ __forceinline__ void gload16(const void* g, void* l) {
    __builtin_amdgcn_global_load_lds((const __attribute__((address_space(1))) unsigned*)g,
                                     (__attribute__((address_space(3))) unsigned*)l, 16, 0, 0);
}

// ---------------------------------------------------------------- zero (f4)  (fallback)
__global__ __launch_bounds__(256) void zero_f4(float4* __restrict__ p, int n4) {
    int i = blockIdx.x * 256 + threadIdx.x;
    if (i < n4) p[i] = make_float4(0.f, 0.f, 0.f, 0.f);
}

// ---------------------------------------------------------------- adjacency (tri +prep +partials +Xo +Ds-zero)
// z 0..3 : upper-tri 64x64 tiles -> As/Abf (tile + LDS-transposed mirror) + Pp row/col partials
// z 4    : prep — W01t[g][f]=(W0@W1)[f][g]; W2t[f2][g]=W2[g][f2]; Xbf cast
// z 5    : Ds-zero (only when scratch lives in d_ws)
__global__ __launch_bounds__(256) void adj_kernel(const float* __restrict__ X,
                                                  const float* __restrict__ a_link,
                                                  const float* __restrict__ W0,
                                                  const float* __restrict__ W1,
                                                  const float* __restrict__ W2,
                                                  float* __restrict__ As,
                                                  unsigned short* __restrict__ Abf,
                                                  unsigned short* __restrict__ Xbf,
                                                  unsigned short* __restrict__ W01t,
                                                  unsigned short* __restrict__ W2t,
                                                  float* __restrict__ Pp,
                                                  float* __restrict__ Xo,
                                                  float* __restrict__ Zd) {
    int tid = threadIdx.x;
    if (blockIdx.z == 5) {                        // Ds-zero layer: 4.2M floats over NTRI blocks
        if (Zd) {
            float4* Z = (float4*)Zd;
#pragma unroll
            for (int it = 0; it < 31; it++) {
                int i = it * (NTRI * 256) + blockIdx.x * 256 + tid;
                if (i < 1048576) Z[i] = make_float4(0.f, 0.f, 0.f, 0.f);
            }
        }
        return;
    }
    if (blockIdx.z == 4) {                        // prep: 65536 items over NTRI blocks
        for (int it = 0; it < 2; it++) {
            int q = it * (NTRI * 256) + blockIdx.x * 256 + tid;
            if (q >= 65536) break;
            if (q < 16384) {                      // W01t[g][f] = sum_h W0[f][h]*W1[h][g]
                int g = q >> 7, f = q & 127;
                float s = 0.f;
                for (int h = 0; h < 128; h++) s += W0[f * 128 + h] * W1[h * 128 + g];
                W01t[q] = f2bf(s);
            } else if (q < 32768) {               // W2t[f2][g] = W2[g][f2]
                int e = q - 16384;
                int f2 = e >> 7, g = e & 127;
                W2t[e] = f2bf(W2[g * 128 + f2]);
            } else {                              // Xbf cast: 32768 items x 4 float4
                int u = q - 32768;
#pragma unroll
                for (int p = 0; p < 4; p++) {
                    size_t i4 = (size_t)u + (size_t)p * 32768;
                    float4 v = *(const float4*)&X[i4 * 4];
                    us4 o; o[0] = f2bf(v.x); o[1] = f2bf(v.y); o[2] = f2bf(v.z); o[3] = f2bf(v.w);
                    *(us4*)&Xbf[i4 * 4] = o;
                }
            }
        }
        return;
    }
    // ---- upper-triangular tile (ta, tb), ta <= tb ----
    int b = blockIdx.z;
    int t = blockIdx.x;                           // 0..135
    int ta = 0, rem = t;
    while (rem >= 16 - ta) { rem -= 16 - ta; ta++; }
    int tb = ta + rem;
    int i0 = ta * 64, j0 = tb * 64;
    bool diag = (ta == tb);

    __shared__ float hi[64][FOBS + 1];
    __shared__ float hj[64][FOBS + 1];
    __shared__ float av[FOBS];
    __shared__ float part_r[64][16];
    __shared__ float part_c[64][16];
    __shared__ float st[64][68];                  // transposed tile [j-local][i-local]
    const float* Xb = X + (size_t)b * NN * FF;
    if (diag) {                                   // Xo passthrough for this row-panel
#pragma unroll
        for (int p = 0; p < 8; p++) {
            int c = p * 256 + tid, r = c >> 5, qq = c & 31;
            *(float4*)&Xo[((size_t)b * NN + i0 + r) * FF + qq * 4] =
                *(const float4*)&Xb[(size_t)(i0 + r) * FF + qq * 4];
        }
    }
#pragma unroll
    for (int l = 0; l < 8; l++) {
        int idx = l * 256 + tid;
        int r = idx >> 5, f = idx & 31;
        hi[r][f] = Xb[(size_t)(i0 + r) * FF + f];
        hj[r][f] = Xb[(size_t)(j0 + r) * FF + f];
    }
    if (tid < FOBS) av[tid] = a_link[tid];
    __syncthreads();

    int ty = tid >> 4, tx = tid & 15;
    int ir = ty * 4, jc = tx * 4;
    float acc[4][4] = {};
#pragma unroll
    for (int f = 0; f < FOBS; f++) {
        float a = av[f];
        float x[4], y[4];
#pragma unroll
        for (int r = 0; r < 4; r++) x[r] = hi[ir + r][f];
#pragma unroll
        for (int c = 0; c < 4; c++) y[c] = hj[jc + c][f];
#pragma unroll
        for (int r = 0; r < 4; r++)
#pragma unroll
            for (int c = 0; c < 4; c++)
                acc[r][c] += fabsf(x[r] - y[c]) * a;
    }
    float* Ab = As + (size_t)b * NN * NN;
    unsigned short* Abb = Abf + (size_t)b * NN * NN;
    float cs[4] = {0.f, 0.f, 0.f, 0.f};
#pragma unroll
    for (int r = 0; r < 4; r++) {
        int gi = i0 + ir + r;
        float vv[4]; float rs = 0.f;
#pragma unroll
        for (int c = 0; c < 4; c++) {
            int gj = j0 + jc + c;
            float sg = 1.f / (1.f + __expf(-acc[r][c]));
            vv[c] = (gi == gj) ? 0.f : sg;
            rs += vv[c];
        }
        *(float4*)&Ab[(size_t)gi * NN + (j0 + jc)] = make_float4(vv[0], vv[1], vv[2], vv[3]);
        us4 o; o[0] = f2bf(vv[0]); o[1] = f2bf(vv[1]); o[2] = f2bf(vv[2]); o[3] = f2bf(vv[3]);
        *(us4*)&Abb[(size_t)gi * NN + (j0 + jc)] = o;
        part_r[ir + r][tx] = rs;
        if (!diag) {
#pragma unroll
            for (int c = 0; c < 4; c++) { st[jc + c][ir + r] = vv[c]; cs[c] += vv[c]; }
        }
    }
    if (!diag) {
#pragma unroll
        for (int c = 0; c < 4; c++) part_c[jc + c][ty] = cs[c];
    }
    __syncthreads();
    if (tid < 64) {                               // row sums -> Pp[i][tb]
        float s = 0.f;
#pragma unroll
        for (int k = 0; k < 16; k++) s += part_r[tid][k];
        Pp[((size_t)b * NN + i0 + tid) * 16 + tb] = s;
    }
    if (!diag) {
        // mirror tile: As[j][i] = As[i][j] (coalesced via LDS transpose)
#pragma unroll
        for (int r2 = 0; r2 < 4; r2++) {
            int jl = ty * 4 + r2;
            int gj = j0 + jl;
            float4 v4 = *(const float4*)&st[jl][tx * 4];
            *(float4*)&Ab[(size_t)gj * NN + (i0 + tx * 4)] = v4;
            us4 o; o[0] = f2bf(v4.x); o[1] = f2bf(v4.y); o[2] = f2bf(v4.z); o[3] = f2bf(v4.w);
            *(us4*)&Abb[(size_t)gj * NN + (i0 + tx * 4)] = o;
        }
        if (tid < 64) {                           // col sums -> Pp[j][ta]
            float s = 0.f;
#pragma unroll
            for (int k = 0; k < 16; k++) s += part_c[tid][k];
            Pp[((size_t)b * NN + j0 + tid) * 16 + ta] = s;
        }
    }
}

// ---------------------------------------------------------------- t0 (MFMA)
// T0[f2][n] = dinv[n] * ((X @ W0W1) @ W2)^T  -- the z0 panel (D^-1/2 X Wc).
__global__ __launch_bounds__(256) void t0_kernel(const unsigned short* __restrict__ Xbf,
                                                 const unsigned short* __restrict__ W01t,
                                                 const unsigned short* __restrict__ W2t,
                                                 const float* __restrict__ Pp,
                                                 unsigned short* __restrict__ TtX) {
    int bid = blockIdx.x;
    int b = bid >> 6, n0 = (bid & 63) * 16;
    __shared__ unsigned short W01s[128 * 128];
    __shared__ unsigned short W2s[128 * 128];
    __shared__ unsigned short Xps[16 * 128];
    __shared__ unsigned short Ps[16 * 128];
    __shared__ float dinv_s[16];
    int tid = threadIdx.x;
    const unsigned short* Xb = Xbf + (size_t)b * NN * DD;
    {                                             // dinv for rows n0..n0+15 (drains its load)
        int r = tid >> 4, p = tid & 15;
        float s = Pp[((size_t)b * NN + n0 + r) * 16 + p];
        s += __shfl_xor(s, 1);
        s += __shfl_xor(s, 2);
        s += __shfl_xor(s, 4);
        s += __shfl_xor(s, 8);
        if (p == 0) dinv_s[r] = rsqrtf(1.f + s);
    }
#pragma unroll
    for (int p = 0; p < 8; p++) {
        int c = p * 256 + tid, row = c >> 4, kc = c & 15;
        gload16(W01t + (size_t)row * 128 + ((kc ^ (row & 7)) * 8), W01s + (size_t)c * 8);
    }
#pragma unroll
    for (int p = 0; p < 8; p++) {
        int c = p * 256 + tid, row = c >> 4, kc = c & 15;
        gload16(W2t + (size_t)row * 128 + ((kc ^ (row & 7)) * 8), W2s + (size_t)c * 8);
    }
    {
        int c = tid, row = c >> 4, kc = c & 15;
        gload16(Xb + (size_t)(n0 + row) * 128 + ((kc ^ (row & 7)) * 8), Xps + (size_t)c * 8);
    }
    __syncthreads();

    int w = tid >> 6, l = tid & 63, lr = l & 15, lg = l >> 4;
    ffrag pacc[2] = {};                           // P[g][n] = (X @ W01)^T
#pragma unroll
    for (int ks = 0; ks < 4; ks++) {
        int k0 = ks * 32 + lg * 8;
        bfrag a[2], bb;
#pragma unroll
        for (int rb = 0; rb < 2; rb++) {
            int row = w * 32 + rb * 16 + lr;
            int byt = (row * 256 + k0 * 2) ^ ((row & 7) << 4);
            a[rb] = *(const bfrag*)((const char*)W01s + byt);
        }
        {
            int byt = (lr * 256 + k0 * 2) ^ ((lr & 7) << 4);
            bb = *(const bfrag*)((const char*)Xps + byt);
        }
#pragma unroll
        for (int rb = 0; rb < 2; rb++)
            pacc[rb] = __builtin_amdgcn_mfma_f32_16x16x32_bf16(a[rb], bb, pacc[rb], 0, 0, 0);
    }
#pragma unroll
    for (int rb = 0; rb < 2; rb++) {              // P -> LDS [n][g] swizzled
        int g0 = w * 32 + rb * 16 + lg * 4;
        us4 o;
#pragma unroll
        for (int r = 0; r < 4; r++) o[r] = f2bf(pacc[rb][r]);
        int byt = (lr * 256 + g0 * 2) ^ ((lr & 7) << 4);
        *(us4*)((char*)Ps + byt) = o;
    }
    __syncthreads();
    ffrag tacc[2] = {};                           // y0[f2][n] = (P^T @ W2)^T
#pragma unroll
    for (int ks = 0; ks < 4; ks++) {
        int k0 = ks * 32 + lg * 8;
        bfrag a2[2], b2;
#pragma unroll
        for (int rb = 0; rb < 2; rb++) {
            int row = w * 32 + rb * 16 + lr;
            int byt = (row * 256 + k0 * 2) ^ ((row & 7) << 4);
            a2[rb] = *(const bfrag*)((const char*)W2s + byt);
        }
        {
            int byt = (lr * 256 + k0 * 2) ^ ((lr & 7) << 4);
            b2 = *(const bfrag*)((const char*)Ps + byt);
        }
#pragma unroll
        for (int rb = 0; rb < 2; rb++)
            tacc[rb] = __builtin_amdgcn_mfma_f32_16x16x32_bf16(a2[rb], b2, tacc[rb], 0, 0, 0);
    }
    unsigned short* Tb = TtX + (size_t)b * DD * NN;
    float dv = dinv_s[lr];
#pragma unroll
    for (int rb = 0; rb < 2; rb++)
#pragma unroll
        for (int r = 0; r < 4; r++) {
            int f2 = w * 32 + rb * 16 + lg * 4 + r;
            Tb[(size_t)f2 * NN + n0 + lr] = f2bf(tacc[rb][r] * dv);
        }
}

// ---------------------------------------------------------------- ga (pipelined A-GEMM, split-f, BK=128)
// Block (panel, fh): 64 f-rows, 16 n-cols.  acc = sum_k T[f][k]*A[k][n]
// (A symmetric -> stage A[n][k] rows contiguous).  Epilogue:
//   LAST=0: Tout[f][n] = dinv[n]^2 * (acc + Tin[f][n])      (z' = D^-1 Â z)
//   LAST=1: Hs[n][f]   = relu(dinv[n] * (acc + Tin[f][n]))  (H = D^-1/2 Â z2)
template <int LAST>
__global__ __launch_bounds__(256) void ga_kernel(const unsigned short* __restrict__ Abf,
                                                 const float* __restrict__ Pp,
                                                 const unsigned short* __restrict__ Tin,
                                                 unsigned short* __restrict__ Tout,
                                                 float* __restrict__ HsF) {
    int bid = blockIdx.x;
    int fh = bid & 1, panel = bid >> 1;
    int b = panel >> 6, n0 = (panel & 63) * 16;
    __shared__ unsigned short T_s[3 * 64 * 128];  // 48 KB
    __shared__ unsigned short A_s[3 * 16 * 128];  // 12 KB
    __shared__ float dinv_s[16];
    int tid = threadIdx.x;
    const unsigned short* TbF = Tin + (size_t)b * DD * NN;       // full panel (identity reads)
    const unsigned short* Tb  = TbF + (size_t)fh * 64 * NN;      // this block's f-half
    const unsigned short* Ab  = Abf + (size_t)b * NN * NN;

    {                                             // dinv for own 16 rows (drains its load)
        int r = tid >> 4, p = tid & 15;
        float s = Pp[((size_t)b * NN + n0 + r) * 16 + p];
        s += __shfl_xor(s, 1);
        s += __shfl_xor(s, 2);
        s += __shfl_xor(s, 4);
        s += __shfl_xor(s, 8);
        if (p == 0) dinv_s[r] = rsqrtf(1.f + s);
    }
    auto stageT = [&](int buf, int kt) {          // uniform 5 gload16 per thread
#pragma unroll
        for (int p = 0; p < 4; p++) {             // T tile 64x128 = 1024 chunks
            int c = p * 256 + tid, row = c >> 4, kc = c & 15;
            gload16(Tb + (size_t)row * NN + kt + ((kc ^ (row & 7)) * 8),
                    T_s + (size_t)buf * (64 * 128) + (size_t)c * 8);
        }
        int c = tid, row = c >> 4, kc = c & 15;   // A tile 16x128 = 256 chunks
        gload16(Ab + (size_t)(n0 + row) * NN + kt + ((kc ^ (row & 7)) * 8),
                A_s + (size_t)buf * (16 * 128) + (size_t)c * 8);
    };
    stageT(0, 0);
    stageT(1, 128);

    int w = tid >> 6, l = tid & 63, lr = l & 15, lg = l >> 4;
    ffrag acc = {};
    int cur = 0, sb = 2;
    for (int tt = 0; tt < 8; tt++) {
        if (tt <= 5) stageT(sb, (tt + 2) * 128);
        if (tt < 6)       asm volatile("s_waitcnt vmcnt(10)" ::: "memory");
        else if (tt == 6) asm volatile("s_waitcnt vmcnt(5)"  ::: "memory");
        else              asm volatile("s_waitcnt vmcnt(0)"  ::: "memory");
        __builtin_amdgcn_s_barrier();
        asm volatile("" ::: "memory");
        const unsigned short* Tc = T_s + (size_t)cur * (64 * 128);
        const unsigned short* Ac = A_s + (size_t)cur * (16 * 128);
#pragma unroll
        for (int ks = 0; ks < 4; ks++) {
            int k0 = ks * 32 + lg * 8;
            bfrag a, bb;
            {
                int row = w * 16 + lr;
                int byt = (row * 256 + k0 * 2) ^ ((row & 7) << 4);
                a = *(const bfrag*)((const char*)Tc + byt);
            }
            {
                int byt = (lr * 256 + k0 * 2) ^ ((lr & 7) << 4);
                bb = *(const bfrag*)((const char*)Ac + byt);
            }
            acc = __builtin_amdgcn_mfma_f32_16x16x32_bf16(a, bb, acc, 0, 0, 0);
        }
        asm volatile("s_waitcnt lgkmcnt(0)" ::: "memory");
        __builtin_amdgcn_s_barrier();             // all reads of buf done before overwrite
        cur = (cur == 2) ? 0 : cur + 1;
        sb = (sb == 2) ? 0 : sb + 1;
    }

    int nl = lr;
    float dv = dinv_s[nl];
    int f0 = fh * 64 + w * 16 + lg * 4;
    if (LAST) {                                   // H = relu(dinv*(acc + z2)), f32 node-major
        float v[4];
#pragma unroll
        for (int r = 0; r < 4; r++) {
            float idv = bf2f(TbF[(size_t)(f0 + r) * NN + n0 + nl]);
            v[r] = fmaxf((acc[r] + idv) * dv, 0.f);
        }
        *(float4*)&HsF[((size_t)b * NN + n0 + nl) * DD + f0] = make_float4(v[0], v[1], v[2], v[3]);
    } else {                                      // z' = dinv^2*(acc + z)
        float dv2 = dv * dv;
        unsigned short* Ob = Tout + (size_t)b * DD * NN;
#pragma unroll
        for (int r = 0; r < 4; r++) {
            float idv = bf2f(TbF[(size_t)(f0 + r) * NN + n0 + nl]);
            Ob[(size_t)(f0 + r) * NN + n0 + nl] = f2bf((acc[r] + idv) * dv2);
        }
    }
}

// ---------------------------------------------------------------- launcher
extern "C" void kernel_launch(void* const* d_in, const int* in_sizes, int n_in,
                              void* d_out, int out_size, void* d_ws, size_t ws_size,
                              hipStream_t stream) {
    const float* X      = (const float*)d_in[0];
    const float* a_link = (const float*)d_in[1];
    const float* W0     = (const float*)d_in[2];
    const float* W1     = (const float*)d_in[3];
    const float* W2     = (const float*)d_in[4];
    float* out = (float*)d_out;

    const size_t HND = (size_t)BB * NN * DD;      // 524288
    const size_t HNN = (size_t)BB * NN * NN;      // 4194304
    float* Hs = out;
    float* As = out + HND;
    float* Xo = out + HND + HNN;
    float* Ds = out + 2 * HND + HNN;

    // scratch (bytes): Abf 8388608 | Xbf 1048576 | TtX 1048576 | TtY 1048576
    //                  | W01t 32768 | W2t 32768 | Pp 262144  => 11,862,016
    const size_t NEED = 11862016;
    bool usews = (ws_size >= NEED);
    char* scr = usews ? (char*)d_ws : (char*)Ds;

    unsigned short* Abf  = (unsigned short*)(scr);
    unsigned short* Xbf  = (unsigned short*)(scr + 8388608);
    unsigned short* TtX  = (unsigned short*)(scr + 9437184);
    unsigned short* TtY  = (unsigned short*)(scr + 10485760);
    unsigned short* W01t = (unsigned short*)(scr + 11534336);
    unsigned short* W2t  = (unsigned short*)(scr + 11567104);
    float* Pp            = (float*)(scr + 11599872);

    adj_kernel<<<dim3(NTRI, 1, usews ? 6 : 5), 256, 0, stream>>>(
        X, a_link, W0, W1, W2, As, Abf, Xbf, W01t, W2t, Pp, Xo, usews ? Ds : nullptr);
    t0_kernel<<<dim3(256), 256, 0, stream>>>(Xbf, W01t, W2t, Pp, TtX);
    ga_kernel<0><<<dim3(512), 256, 0, stream>>>(Abf, Pp, TtX, TtY, nullptr);
    ga_kernel<0><<<dim3(512), 256, 0, stream>>>(Abf, Pp, TtY, TtX, nullptr);
    ga_kernel<1><<<dim3(512), 256, 0, stream>>>(Abf, Pp, TtX, nullptr, Hs);

    if (!usews)                                    // scratch lived in Ds: zero it now
        zero_f4<<<dim3(4096), 256, 0, stream>>>((float4*)Ds, (int)(HNN / 4));
}

// Round 11
// 51.538 us; speedup vs baseline: 1.0508x; 1.0508x over previous
//
#include <hip/hip_runtime.h>
#include <math.h>

#define BB 4
#define NN 1024
#define FF 128
#define DD 128
#define FOBS 32

typedef __attribute__((ext_vector_type(8))) short bfrag;   // 8 bf16 = 4 VGPR
typedef __attribute__((ext_vector_type(4))) float ffrag;   // 4 f32 acc
typedef __attribute__((ext_vector_type(4))) unsigned short us4;
typedef __attribute__((ext_vector_type(2))) float f32x2;
typedef __attribute__((ext_vector_type(2))) unsigned int u32x2;

__device__ __forceinline__ unsigned short f2bf(float x) {
    unsigned u = __builtin_bit_cast(unsigned, x);
    u += 0x7fffu + ((u >> 16) & 1u);              // RNE
    return (unsigned short)(u >> 16);
}
__device__ __forceinline__ float bf2f(unsigned short s) {
    unsigned u = (unsigned)s << 16;
    return __builtin_bit_cast(float, u);
}
__device__ __forceinline__ void gload16(const void* g, void* l) {
    __builtin_amdgcn_global_load_lds((const __attribute__((address_space(1))) unsigned*)g,
                                     (__attribute__((address_space(3))) unsigned*)l, 16, 0, 0);
}
__device__ __forceinline__ f32x2 abs2(f32x2 v) {   // packed |.| via bit-and
    u32x2 u = __builtin_bit_cast(u32x2, v);
    u &= 0x7fffffffu;
    return __builtin_bit_cast(f32x2, u);
}

// ---------------------------------------------------------------- zero (f4)  (fallback)
__global__ __launch_bounds__(256) void zero_f4(float4* __restrict__ p, int n4) {
    int i = blockIdx.x * 256 + threadIdx.x;
    if (i < n4) p[i] = make_float4(0.f, 0.f, 0.f, 0.f);
}

// ---------------------------------------------------------------- adjacency (+prep +partials +Xo +Ds-zero)
// z 0..3 : A 64x64 tiles -> As f32 (output) + Abf bf16 (GEMM operand) + Pp partial row-sums
// z 4    : prep — W01t[g][f]=(W0@W1)[f][g] bf16; W2t[f2][g]=W2[g][f2] bf16; Xbf cast
// z 5    : Ds-zero (only when scratch lives in d_ws)
__global__ __launch_bounds__(256) void adj_kernel(const float* __restrict__ X,
                                                  const float* __restrict__ a_link,
                                                  const float* __restrict__ W0,
                                                  const float* __restrict__ W1,
                                                  const float* __restrict__ W2,
                                                  float* __restrict__ As,
                                                  unsigned short* __restrict__ Abf,
                                                  unsigned short* __restrict__ Xbf,
                                                  unsigned short* __restrict__ W01t,
                                                  unsigned short* __restrict__ W2t,
                                                  float* __restrict__ Pp,
                                                  float* __restrict__ Xo,
                                                  float* __restrict__ Zd) {
    int tid = threadIdx.x;
    if (blockIdx.z == 5) {                        // Ds-zero layer
        if (Zd) {
            int q = blockIdx.y * 16 + blockIdx.x; // 0..255
            float4* Z = (float4*)Zd;
#pragma unroll
            for (int p = 0; p < 16; p++)
                Z[(size_t)q * 4096 + p * 256 + tid] = make_float4(0.f, 0.f, 0.f, 0.f);
        }
        return;
    }
    if (blockIdx.z == 4) {                        // prep
        int q = (blockIdx.y * 16 + blockIdx.x) * 256 + tid;   // 0..65535
        if (q < 16384) {                          // W01t[g][f] = sum_h W0[f][h]*W1[h][g]
            int g = q >> 7, f = q & 127;
            float s = 0.f;
            for (int h = 0; h < 128; h++) s += W0[f * 128 + h] * W1[h * 128 + g];
            W01t[q] = f2bf(s);
        } else if (q < 32768) {                   // W2t[f2][g] = W2[g][f2]
            int e = q - 16384;
            int f2 = e >> 7, g = e & 127;
            W2t[e] = f2bf(W2[g * 128 + f2]);
        } else {                                  // Xbf cast: 32768 thr x 4 float4
            int u = q - 32768;
#pragma unroll
            for (int p = 0; p < 4; p++) {
                size_t i4 = (size_t)u + (size_t)p * 32768;
                float4 v = *(const float4*)&X[i4 * 4];
                us4 o; o[0] = f2bf(v.x); o[1] = f2bf(v.y); o[2] = f2bf(v.z); o[3] = f2bf(v.w);
                *(us4*)&Xbf[i4 * 4] = o;
            }
        }
        return;
    }
    int b = blockIdx.z, i0 = blockIdx.y * 64, j0 = blockIdx.x * 64;
    __shared__ float hi[64][FOBS + 1];
    __shared__ float hj[64][FOBS + 1];
    __shared__ float av[FOBS];
    __shared__ float part_s[64][16];
    const float* Xb = X + (size_t)b * NN * FF;
    if (j0 == 0) {                                // Xo passthrough for this row-panel
#pragma unroll
        for (int p = 0; p < 8; p++) {
            int c = p * 256 + tid, r = c >> 5, qq = c & 31;
            *(float4*)&Xo[((size_t)b * NN + i0 + r) * FF + qq * 4] =
                *(const float4*)&Xb[(size_t)(i0 + r) * FF + qq * 4];
        }
    }
#pragma unroll
    for (int l = 0; l < 8; l++) {
        int idx = l * 256 + tid;
        int r = idx >> 5, f = idx & 31;
        hi[r][f] = Xb[(size_t)(i0 + r) * FF + f];
        hj[r][f] = Xb[(size_t)(j0 + r) * FF + f];
    }
    if (tid < FOBS) av[tid] = a_link[tid];
    __syncthreads();

    int ty = tid >> 4, tx = tid & 15;
    int ir = ty * 4, jc = tx * 4;
    f32x2 acc2[4][4] = {};                        // packed f-pair accumulators (v_pk_fma_f32)
#pragma unroll
    for (int f = 0; f < FOBS; f += 2) {
        f32x2 a2; a2[0] = av[f]; a2[1] = av[f + 1];
        f32x2 x2[4], y2[4];
#pragma unroll
        for (int r = 0; r < 4; r++) { x2[r][0] = hi[ir + r][f]; x2[r][1] = hi[ir + r][f + 1]; }
#pragma unroll
        for (int c = 0; c < 4; c++) { y2[c][0] = hj[jc + c][f]; y2[c][1] = hj[jc + c][f + 1]; }
#pragma unroll
        for (int r = 0; r < 4; r++)
#pragma unroll
            for (int c = 0; c < 4; c++)
                acc2[r][c] += abs2(x2[r] - y2[c]) * a2;
    }
    float* Ab = As + (size_t)b * NN * NN;
    unsigned short* Abb = Abf + (size_t)b * NN * NN;
#pragma unroll
    for (int r = 0; r < 4; r++) {
        int gi = i0 + ir + r;
        float vv[4]; float rs = 0.f;
#pragma unroll
        for (int c = 0; c < 4; c++) {
            int gj = j0 + jc + c;
            float e = acc2[r][c][0] + acc2[r][c][1];
            float sg = 1.f / (1.f + __expf(-e));
            vv[c] = (gi == gj) ? 0.f : sg;
            rs += vv[c];
        }
        *(float4*)&Ab[(size_t)gi * NN + (j0 + jc)] = make_float4(vv[0], vv[1], vv[2], vv[3]);
        us4 o; o[0] = f2bf(vv[0]); o[1] = f2bf(vv[1]); o[2] = f2bf(vv[2]); o[3] = f2bf(vv[3]);
        *(us4*)&Abb[(size_t)gi * NN + (j0 + jc)] = o;
        part_s[ir + r][tx] = rs;
    }
    __syncthreads();
    if (tid < 64) {                               // 16 partials -> one f32 per row
        float s = 0.f;
#pragma unroll
        for (int k = 0; k < 16; k++) s += part_s[tid][k];
        Pp[((size_t)b * NN + i0 + tid) * 16 + blockIdx.x] = s;
    }
}

// ---------------------------------------------------------------- t0 (MFMA)
// T0[f2][n] = dinv[n] * ((X @ W0W1) @ W2)^T  -- the z0 panel (D^-1/2 X Wc)^T.
__global__ __launch_bounds__(256) void t0_kernel(const unsigned short* __restrict__ Xbf,
                                                 const unsigned short* __restrict__ W01t,
                                                 const unsigned short* __restrict__ W2t,
                                                 const float* __restrict__ Pp,
                                                 unsigned short* __restrict__ TtX) {
    int bid = blockIdx.x;
    int b = bid >> 6, n0 = (bid & 63) * 16;
    __shared__ unsigned short W01s[128 * 128];
    __shared__ unsigned short W2s[128 * 128];
    __shared__ unsigned short Xps[16 * 128];
    __shared__ unsigned short Ps[16 * 128];
    __shared__ float dinv_s[16];
    int tid = threadIdx.x;
    const unsigned short* Xb = Xbf + (size_t)b * NN * DD;
    {                                             // dinv for rows n0..n0+15 (drains its load)
        int r = tid >> 4, p = tid & 15;
        float s = Pp[((size_t)b * NN + n0 + r) * 16 + p];
        s += __shfl_xor(s, 1);
        s += __shfl_xor(s, 2);
        s += __shfl_xor(s, 4);
        s += __shfl_xor(s, 8);
        if (p == 0) dinv_s[r] = rsqrtf(1.f + s);
    }
#pragma unroll
    for (int p = 0; p < 8; p++) {
        int c = p * 256 + tid, row = c >> 4, kc = c & 15;
        gload16(W01t + (size_t)row * 128 + ((kc ^ (row & 7)) * 8), W01s + (size_t)c * 8);
    }
#pragma unroll
    for (int p = 0; p < 8; p++) {
        int c = p * 256 + tid, row = c >> 4, kc = c & 15;
        gload16(W2t + (size_t)row * 128 + ((kc ^ (row & 7)) * 8), W2s + (size_t)c * 8);
    }
    {
        int c = tid, row = c >> 4, kc = c & 15;
        gload16(Xb + (size_t)(n0 + row) * 128 + ((kc ^ (row & 7)) * 8), Xps + (size_t)c * 8);
    }
    __syncthreads();

    int w = tid >> 6, l = tid & 63, lr = l & 15, lg = l >> 4;
    ffrag pacc[2] = {};                           // P[g][n] = (X @ W01)^T
#pragma unroll
    for (int ks = 0; ks < 4; ks++) {
        int k0 = ks * 32 + lg * 8;
        bfrag a[2], bb;
#pragma unroll
        for (int rb = 0; rb < 2; rb++) {
            int row = w * 32 + rb * 16 + lr;
            int byt = (row * 256 + k0 * 2) ^ ((row & 7) << 4);
            a[rb] = *(const bfrag*)((const char*)W01s + byt);
        }
        {
            int byt = (lr * 256 + k0 * 2) ^ ((lr & 7) << 4);
            bb = *(const bfrag*)((const char*)Xps + byt);
        }
#pragma unroll
        for (int rb = 0; rb < 2; rb++)
            pacc[rb] = __builtin_amdgcn_mfma_f32_16x16x32_bf16(a[rb], bb, pacc[rb], 0, 0, 0);
    }
#pragma unroll
    for (int rb = 0; rb < 2; rb++) {              // P -> LDS [n][g] swizzled
        int g0 = w * 32 + rb * 16 + lg * 4;
        us4 o;
#pragma unroll
        for (int r = 0; r < 4; r++) o[r] = f2bf(pacc[rb][r]);
        int byt = (lr * 256 + g0 * 2) ^ ((lr & 7) << 4);
        *(us4*)((char*)Ps + byt) = o;
    }
    __syncthreads();
    ffrag tacc[2] = {};                           // y0[f2][n] = (P^T @ W2)^T
#pragma unroll
    for (int ks = 0; ks < 4; ks++) {
        int k0 = ks * 32 + lg * 8;
        bfrag a2[2], b2;
#pragma unroll
        for (int rb = 0; rb < 2; rb++) {
            int row = w * 32 + rb * 16 + lr;
            int byt = (row * 256 + k0 * 2) ^ ((row & 7) << 4);
            a2[rb] = *(const bfrag*)((const char*)W2s + byt);
        }
        {
            int byt = (lr * 256 + k0 * 2) ^ ((lr & 7) << 4);
            b2 = *(const bfrag*)((const char*)Ps + byt);
        }
#pragma unroll
        for (int rb = 0; rb < 2; rb++)
            tacc[rb] = __builtin_amdgcn_mfma_f32_16x16x32_bf16(a2[rb], b2, tacc[rb], 0, 0, 0);
    }
    unsigned short* Tb = TtX + (size_t)b * DD * NN;
    float dv = dinv_s[lr];
#pragma unroll
    for (int rb = 0; rb < 2; rb++)
#pragma unroll
        for (int r = 0; r < 4; r++) {
            int f2 = w * 32 + rb * 16 + lg * 4 + r;
            Tb[(size_t)f2 * NN + n0 + lr] = f2bf(tacc[rb][r] * dv);
        }
}

// ---------------------------------------------------------------- ga (pipelined A-GEMM, split-f)
// Block (panel, fh): 64 f-rows (fh half), 16 n-cols.  acc = sum_k T[f][k]*A[k][n]
// (A symmetric -> stage A[n][k] rows contiguous).  Epilogue:
//   LAST=0: Tout[f][n] = dinv[n]^2 * (acc + Tin[f][n])      (z' = D^-1 Â z)
//   LAST=1: Hs[n][f]   = relu(dinv[n] * (acc + Tin[f][n]))  (H = D^-1/2 Â z2)
template <int LAST>
__global__ __launch_bounds__(256) void ga_kernel(const unsigned short* __restrict__ Abf,
                                                 const float* __restrict__ Pp,
                                                 const unsigned short* __restrict__ Tin,
                                                 unsigned short* __restrict__ Tout,
                                                 float* __restrict__ HsF) {
    int bid = blockIdx.x;
    int fh = bid & 1, panel = bid >> 1;
    int b = panel >> 6, n0 = (panel & 63) * 16;
    __shared__ unsigned short T_s[3 * 64 * 64];   // 24 KB
    __shared__ unsigned short A_s[3 * 16 * 64];   // 6 KB
    __shared__ float dinv_s[16];
    int tid = threadIdx.x;
    const unsigned short* TbF = Tin + (size_t)b * DD * NN;       // full panel (identity reads)
    const unsigned short* Tb  = TbF + (size_t)fh * 64 * NN;      // this block's f-half
    const unsigned short* Ab  = Abf + (size_t)b * NN * NN;

    {                                             // dinv for own 16 rows (drains its load)
        int r = tid >> 4, p = tid & 15;
        float s = Pp[((size_t)b * NN + n0 + r) * 16 + p];
        s += __shfl_xor(s, 1);
        s += __shfl_xor(s, 2);
        s += __shfl_xor(s, 4);
        s += __shfl_xor(s, 8);
        if (p == 0) dinv_s[r] = rsqrtf(1.f + s);
    }
    auto stageT = [&](int buf, int kt) {          // uniform 3 gload16 per thread
#pragma unroll
        for (int p = 0; p < 2; p++) {
            int c = p * 256 + tid, row = c >> 3, kc = c & 7;
            gload16(Tb + (size_t)row * NN + kt + ((kc ^ (row & 7)) * 8),
                    T_s + (size_t)buf * (64 * 64) + (size_t)c * 8);
        }
        int c = tid & 127, row = c >> 3, kc = c & 7;   // tid>=128 duplicates, benign
        gload16(Ab + (size_t)(n0 + row) * NN + kt + ((kc ^ (row & 7)) * 8),
                A_s + (size_t)buf * (16 * 64) + (size_t)c * 8);
    };
    stageT(0, 0);
    stageT(1, 64);

    int w = tid >> 6, l = tid & 63, lr = l & 15, lg = l >> 4;
    ffrag acc = {};
    int cur = 0, sb = 2;
    for (int t = 0; t < 16; t++) {
        if (t <= 13) stageT(sb, (t + 2) * 64);
        if (t < 14)       asm volatile("s_waitcnt vmcnt(6)" ::: "memory");
        else if (t == 14) asm volatile("s_waitcnt vmcnt(3)" ::: "memory");
        else              asm volatile("s_waitcnt vmcnt(0)" ::: "memory");
        __builtin_amdgcn_s_barrier();
        asm volatile("" ::: "memory");
        const unsigned short* Tc = T_s + (size_t)cur * (64 * 64);
        const unsigned short* Ac = A_s + (size_t)cur * (16 * 64);
#pragma unroll
        for (int ks = 0; ks < 2; ks++) {
            int k0 = ks * 32 + lg * 8;
            bfrag a, bb;
            {
                int row = w * 16 + lr;
                int byt = (row * 128 + k0 * 2) ^ ((row & 7) << 4);
                a = *(const bfrag*)((const char*)Tc + byt);
            }
            {
                int byt = (lr * 128 + k0 * 2) ^ ((lr & 7) << 4);
                bb = *(const bfrag*)((const char*)Ac + byt);
            }
            acc = __builtin_amdgcn_mfma_f32_16x16x32_bf16(a, bb, acc, 0, 0, 0);
        }
        asm volatile("s_waitcnt lgkmcnt(0)" ::: "memory");
        __builtin_amdgcn_s_barrier();             // all reads of buf done before overwrite
        cur = (cur == 2) ? 0 : cur + 1;
        sb = (sb == 2) ? 0 : sb + 1;
    }

    int nl = lr;
    float dv = dinv_s[nl];
    int f0 = fh * 64 + w * 16 + lg * 4;
    if (LAST) {                                   // H = relu(dinv*(acc + z2)), f32 node-major
        float v[4];
#pragma unroll
        for (int r = 0; r < 4; r++) {
            float idv = bf2f(TbF[(size_t)(f0 + r) * NN + n0 + nl]);
            v[r] = fmaxf((acc[r] + idv) * dv, 0.f);
        }
        *(float4*)&HsF[((size_t)b * NN + n0 + nl) * DD + f0] = make_float4(v[0], v[1], v[2], v[3]);
    } else {                                      // z' = dinv^2*(acc + z)
        float dv2 = dv * dv;
        unsigned short* Ob = Tout + (size_t)b * DD * NN;
#pragma unroll
        for (int r = 0; r < 4; r++) {
            float idv = bf2f(TbF[(size_t)(f0 + r) * NN + n0 + nl]);
            Ob[(size_t)(f0 + r) * NN + n0 + nl] = f2bf((acc[r] + idv) * dv2);
        }
    }
}

// ---------------------------------------------------------------- launcher
extern "C" void kernel_launch(void* const* d_in, const int* in_sizes, int n_in,
                              void* d_out, int out_size, void* d_ws, size_t ws_size,
                              hipStream_t stream) {
    const float* X      = (const float*)d_in[0];
    const float* a_link = (const float*)d_in[1];
    const float* W0     = (const float*)d_in[2];
    const float* W1     = (const float*)d_in[3];
    const float* W2     = (const float*)d_in[4];
    float* out = (float*)d_out;

    const size_t HND = (size_t)BB * NN * DD;      // 524288
    const size_t HNN = (size_t)BB * NN * NN;      // 4194304
    float* Hs = out;
    float* As = out + HND;
    float* Xo = out + HND + HNN;
    float* Ds = out + 2 * HND + HNN;

    // scratch (bytes): Abf 8388608 | Xbf 1048576 | TtX 1048576 | TtY 1048576
    //                  | W01t 32768 | W2t 32768 | Pp 262144  => 11,862,016
    const size_t NEED = 11862016;
    bool usews = (ws_size >= NEED);
    char* scr = usews ? (char*)d_ws : (char*)Ds;

    unsigned short* Abf  = (unsigned short*)(scr);
    unsigned short* Xbf  = (unsigned short*)(scr + 8388608);
    unsigned short* TtX  = (unsigned short*)(scr + 9437184);
    unsigned short* TtY  = (unsigned short*)(scr + 10485760);
    unsigned short* W01t = (unsigned short*)(scr + 11534336);
    unsigned short* W2t  = (unsigned short*)(scr + 11567104);
    float* Pp            = (float*)(scr + 11599872);

    adj_kernel<<<dim3(16, 16, usews ? 6 : 5), 256, 0, stream>>>(
        X, a_link, W0, W1, W2, As, Abf, Xbf, W01t, W2t, Pp, Xo, usews ? Ds : nullptr);
    t0_kernel<<<dim3(256), 256, 0, stream>>>(Xbf, W01t, W2t, Pp, TtX);
    ga_kernel<0><<<dim3(512), 256, 0, stream>>>(Abf, Pp, TtX, TtY, nullptr);
    ga_kernel<0><<<dim3(512), 256, 0, stream>>>(Abf, Pp, TtY, TtX, nullptr);
    ga_kernel<1><<<dim3(512), 256, 0, stream>>>(Abf, Pp, TtX, nullptr, Hs);

    if (!usews)                                    // scratch lived in Ds: zero it now
        zero_f4<<<dim3(4096), 256, 0, stream>>>((float4*)Ds, (int)(HNN / 4));
}

// Round 12
// 48.899 us; speedup vs baseline: 1.1075x; 1.0540x over previous
//
#include <hip/hip_runtime.h>
#include <math.h>

#define BB 4
#define NN 1024
#define FF 128
#define DD 128
#define FOBS 32

typedef __attribute__((ext_vector_type(8))) short bfrag;   // 8 bf16 = 4 VGPR
typedef __attribute__((ext_vector_type(4))) float ffrag;   // 4 f32 acc
typedef __attribute__((ext_vector_type(4))) unsigned short us4;

__device__ __forceinline__ unsigned short f2bf(float x) {
    unsigned u = __builtin_bit_cast(unsigned, x);
    u += 0x7fffu + ((u >> 16) & 1u);              // RNE
    return (unsigned short)(u >> 16);
}
__device__ __forceinline__ float bf2f(unsigned short s) {
    unsigned u = (unsigned)s << 16;
    return __builtin_bit_cast(float, u);
}
__device__ __forceinline__ void gload16(const void* g, void* l) {
    __builtin_amdgcn_global_load_lds((const __attribute__((address_space(1))) unsigned*)g,
                                     (__attribute__((address_space(3))) unsigned*)l, 16, 0, 0);
}
// dinv for 16 rows from 16 f32 partials each; deterministic fixed-order reduce.
__device__ __forceinline__ void compute_dinv16(const float* __restrict__ Pp, int b, int n0,
                                               int tid, float* dinv_s) {
    int r = tid >> 4, p = tid & 15;               // 256 thr -> 16 rows x 16 lanes
    float s = Pp[((size_t)b * NN + n0 + r) * 16 + p];
    s += __shfl_xor(s, 1);
    s += __shfl_xor(s, 2);
    s += __shfl_xor(s, 4);
    s += __shfl_xor(s, 8);
    if (p == 0) dinv_s[r] = rsqrtf(1.f + s);
}

// ---------------------------------------------------------------- zero (f4)  (fallback path)
__global__ __launch_bounds__(256) void zero_f4(float4* __restrict__ p, int n4) {
    int i = blockIdx.x * 256 + threadIdx.x;
    if (i < n4) p[i] = make_float4(0.f, 0.f, 0.f, 0.f);
}

// ---------------------------------------------------------------- adjacency (+prep +partials +Xo +Ds-zero)
__global__ __launch_bounds__(256) void adj_kernel(const float* __restrict__ X,
                                                  const float* __restrict__ a_link,
                                                  const float* __restrict__ W0,
                                                  const float* __restrict__ W1,
                                                  const float* __restrict__ W2,
                                                  float* __restrict__ A,
                                                  unsigned short* __restrict__ Abf,
                                                  unsigned short* __restrict__ Xbf,
                                                  unsigned short* __restrict__ Wt,
                                                  float* __restrict__ Pp,
                                                  float* __restrict__ Xo,
                                                  float* __restrict__ Zd) {
    int tid = threadIdx.x;
    if (blockIdx.z == 5) {                        // Ds-zero layer (only when scratch = d_ws)
        if (Zd) {
            int q = blockIdx.y * 16 + blockIdx.x; // 0..255
            float4* Z = (float4*)Zd;
#pragma unroll
            for (int p = 0; p < 16; p++)
                Z[(size_t)q * 4096 + p * 256 + tid] = make_float4(0.f, 0.f, 0.f, 0.f);
        }
        return;
    }
    if (blockIdx.z == 4) {                        // prep: Wt casts + X->bf16
        int q = (blockIdx.y * 16 + blockIdx.x) * 256 + tid;   // 0..65535
        if (q < 49152) {
            int m = q >> 14, rem = q & 16383, fp = rem >> 7, f = rem & 127;
            const float* W = (m == 0) ? W0 : (m == 1) ? W1 : W2;
            Wt[q] = f2bf(W[(size_t)f * 128 + fp]);
        } else {
            int u = q - 49152;                    // 0..16383, 8 float4 each
#pragma unroll
            for (int p = 0; p < 8; p++) {
                size_t i4 = (size_t)u + (size_t)p * 16384;
                float4 v = *(const float4*)&X[i4 * 4];
                us4 o; o[0] = f2bf(v.x); o[1] = f2bf(v.y); o[2] = f2bf(v.z); o[3] = f2bf(v.w);
                *(us4*)&Xbf[i4 * 4] = o;
            }
        }
        return;
    }
    int b = blockIdx.z, i0 = blockIdx.y * 64, j0 = blockIdx.x * 64;
    __shared__ float hi[64][FOBS + 1];
    __shared__ float hj[64][FOBS + 1];
    __shared__ float av[FOBS];
    __shared__ float part_s[64][16];
    const float* Xb = X + (size_t)b * NN * FF;
    if (j0 == 0) {                                // Xo passthrough for this row-panel
#pragma unroll
        for (int p = 0; p < 8; p++) {
            int c = p * 256 + tid, r = c >> 5, qq = c & 31;
            *(float4*)&Xo[((size_t)b * NN + i0 + r) * FF + qq * 4] =
                *(const float4*)&Xb[(size_t)(i0 + r) * FF + qq * 4];
        }
    }
#pragma unroll
    for (int l = 0; l < 8; l++) {
        int idx = l * 256 + tid;
        int r = idx >> 5, f = idx & 31;
        hi[r][f] = Xb[(size_t)(i0 + r) * FF + f];
        hj[r][f] = Xb[(size_t)(j0 + r) * FF + f];
    }
    if (tid < FOBS) av[tid] = a_link[tid];
    __syncthreads();

    int ty = tid >> 4, tx = tid & 15;
    int ir = ty * 4, jc = tx * 4;
    float acc[4][4] = {};
#pragma unroll
    for (int f = 0; f < FOBS; f++) {
        float a = av[f];
        float x[4], y[4];
#pragma unroll
        for (int r = 0; r < 4; r++) x[r] = hi[ir + r][f];
#pragma unroll
        for (int c = 0; c < 4; c++) y[c] = hj[jc + c][f];
#pragma unroll
        for (int r = 0; r < 4; r++)
#pragma unroll
            for (int c = 0; c < 4; c++)
                acc[r][c] += fabsf(x[r] - y[c]) * a;
    }
    float* Ab = A + (size_t)b * NN * NN;
    unsigned short* Abb = Abf + (size_t)b * NN * NN;
#pragma unroll
    for (int r = 0; r < 4; r++) {
        int gi = i0 + ir + r;
        float vv[4];
        float rs = 0.f;
#pragma unroll
        for (int c = 0; c < 4; c++) {
            int gj = j0 + jc + c;
            float sg = 1.f / (1.f + __expf(-acc[r][c]));
            vv[c] = (gi == gj) ? 0.f : sg;
            rs += vv[c];
        }
        *(float4*)&Ab[(size_t)gi * NN + (j0 + jc)] = make_float4(vv[0], vv[1], vv[2], vv[3]);
        us4 o; o[0] = f2bf(vv[0]); o[1] = f2bf(vv[1]); o[2] = f2bf(vv[2]); o[3] = f2bf(vv[3]);
        *(us4*)&Abb[(size_t)gi * NN + (j0 + jc)] = o;
        part_s[ir + r][tx] = rs;                  // each (row, tx) slot written once
    }
    __syncthreads();
    if (tid < 64) {                               // 16 partials -> one f32 per row
        float s = 0.f;
#pragma unroll
        for (int k = 0; k < 16; k++) s += part_s[tid][k];
        Pp[((size_t)b * NN + i0 + tid) * 16 + blockIdx.x] = s;
    }
}

// ---------------------------------------------------------------- gw0 (MFMA, 16-node panels)
// Tt[f'][n] = dinv[n] * sum_f Wt0[f'][f] * Xbf[n][f]
__global__ __launch_bounds__(256) void gw0_kernel(const unsigned short* __restrict__ Xbf,
                                                  const unsigned short* __restrict__ Wt0,
                                                  const float* __restrict__ Pp,
                                                  unsigned short* __restrict__ TtOut) {
    int b = blockIdx.y;
    int n0 = blockIdx.x * 16;
    __shared__ unsigned short Wt_s[128 * 128];
    __shared__ unsigned short H_s[16 * 128];
    __shared__ float dinv_s[16];
    int tid = threadIdx.x;
    compute_dinv16(Pp, b, n0, tid, dinv_s);
    const unsigned short* Hb = Xbf + (size_t)b * NN * DD;
#pragma unroll
    for (int p = 0; p < 8; p++) {                 // Wt: 2048 chunks
        int c = p * 256 + tid, row = c >> 4, kc = c & 15;
        gload16(Wt0 + (size_t)row * 128 + ((kc ^ (row & 7)) * 8), Wt_s + (size_t)c * 8);
    }
    {                                             // H tile 16x128: 256 chunks
        int c = tid, row = c >> 4, kc = c & 15;
        gload16(Hb + (size_t)(n0 + row) * 128 + ((kc ^ (row & 7)) * 8), H_s + (size_t)c * 8);
    }
    __syncthreads();

    int w = tid >> 6, l = tid & 63, lr = l & 15, lg = l >> 4;
    ffrag acc[2] = {};
#pragma unroll
    for (int ks = 0; ks < 4; ks++) {
        int k0 = ks * 32 + lg * 8;
        bfrag a[2], bb;
#pragma unroll
        for (int rb = 0; rb < 2; rb++) {
            int row = w * 32 + rb * 16 + lr;
            int byt = (row * 256 + k0 * 2) ^ ((row & 7) << 4);
            a[rb] = *(const bfrag*)((const char*)Wt_s + byt);
        }
        {
            int row = lr;
            int byt = (row * 256 + k0 * 2) ^ ((row & 7) << 4);
            bb = *(const bfrag*)((const char*)H_s + byt);
        }
#pragma unroll
        for (int rb = 0; rb < 2; rb++)
            acc[rb] = __builtin_amdgcn_mfma_f32_16x16x32_bf16(a[rb], bb, acc[rb], 0, 0, 0);
    }
    unsigned short* Ttb = TtOut + (size_t)b * DD * NN;
    int nl = lr;
    float dv = dinv_s[nl];
#pragma unroll
    for (int rb = 0; rb < 2; rb++)
#pragma unroll
        for (int r = 0; r < 4; r++) {
            int f = w * 32 + rb * 16 + lg * 4 + r;
            Ttb[(size_t)f * NN + n0 + nl] = f2bf(acc[rb][r] * dv);
        }
}

// ---------------------------------------------------------------- ga (MFMA, depth-3 pipeline, 16-node panels)
// Dacc[f][n] = sum_k Tt[f][k] * A[k][n] (A symmetric -> read A[n][k] rows contiguous)
// H[n][f] = dinv[n]*(Dacc + Tt[f][n]).
// MODE 0: TtN[f2][n] = dinv[n] * sum_f WtN[f2][f]*H[n][f]; MODE 1: Hs = relu(H) f32.
template <int MODE>
__global__ __launch_bounds__(256) void ga_kernel(const unsigned short* __restrict__ Abf,
                                                 const unsigned short* __restrict__ Tt,
                                                 const unsigned short* __restrict__ WtN,
                                                 const float* __restrict__ Pp,
                                                 unsigned short* __restrict__ TtN,
                                                 float* __restrict__ HsF) {
    int b = blockIdx.y, n0 = blockIdx.x * 16;
    __shared__ unsigned short T_s[3 * 128 * 64];
    __shared__ unsigned short A_s[3 * 16 * 64];
    __shared__ unsigned short W_s[MODE == 0 ? 128 * 128 : 64];
    __shared__ float dinv_s[16];
    int tid = threadIdx.x;
    const unsigned short* Ttb = Tt + (size_t)b * DD * NN;
    const unsigned short* Ab = Abf + (size_t)b * NN * NN;

    compute_dinv16(Pp, b, n0, tid, dinv_s);       // fully drains its own tiny load

    if (MODE == 0) {                              // W for fused epilogue: issued first
#pragma unroll
        for (int p = 0; p < 8; p++) {
            int c = p * 256 + tid, row = c >> 4, kc = c & 15;
            gload16(WtN + (size_t)row * 128 + ((kc ^ (row & 7)) * 8), W_s + (size_t)c * 8);
        }
    }
    auto stageT = [&](int buf, int kt) {          // uniform 5 gload16 per thread
#pragma unroll
        for (int p = 0; p < 4; p++) {
            int c = p * 256 + tid, row = c >> 3, kc = c & 7;
            gload16(Ttb + (size_t)row * NN + kt + ((kc ^ (row & 7)) * 8),
                    T_s + (size_t)buf * (128 * 64) + (size_t)c * 8);
        }
        // A tile 16x64 = 128 chunks; tid>=128 duplicates (same src -> same dest, benign)
        int c = tid & 127, row = c >> 3, kc = c & 7;
        gload16(Ab + (size_t)(n0 + row) * NN + kt + ((kc ^ (row & 7)) * 8),
                A_s + (size_t)buf * (16 * 64) + (size_t)c * 8);
    };
    stageT(0, 0);
    stageT(1, 64);

    int w = tid >> 6, l = tid & 63, lr = l & 15, lg = l >> 4;
    ffrag acc[2] = {};
    int cur = 0, sb = 2;
    for (int t = 0; t < 16; t++) {
        if (t <= 13) stageT(sb, (t + 2) * 64);
        if (t < 14)       asm volatile("s_waitcnt vmcnt(10)" ::: "memory");
        else if (t == 14) asm volatile("s_waitcnt vmcnt(5)"  ::: "memory");
        else              asm volatile("s_waitcnt vmcnt(0)"  ::: "memory");
        __builtin_amdgcn_s_barrier();
        asm volatile("" ::: "memory");
        const unsigned short* Tc = T_s + (size_t)cur * (128 * 64);
        const unsigned short* Ac = A_s + (size_t)cur * (16 * 64);
#pragma unroll
        for (int ks = 0; ks < 2; ks++) {
            int k0 = ks * 32 + lg * 8;
            bfrag a[2], bb;
#pragma unroll
            for (int rb = 0; rb < 2; rb++) {
                int row = w * 32 + rb * 16 + lr;
                int byt = (row * 128 + k0 * 2) ^ ((row & 7) << 4);
                a[rb] = *(const bfrag*)((const char*)Tc + byt);
            }
            {
                int row = lr;
                int byt = (row * 128 + k0 * 2) ^ ((row & 7) << 4);
                bb = *(const bfrag*)((const char*)Ac + byt);
            }
#pragma unroll
            for (int rb = 0; rb < 2; rb++)
                acc[rb] = __builtin_amdgcn_mfma_f32_16x16x32_bf16(a[rb], bb, acc[rb], 0, 0, 0);
        }
        asm volatile("s_waitcnt lgkmcnt(0)" ::: "memory");
        __builtin_amdgcn_s_barrier();             // all reads of buf done before overwrite
        cur = (cur == 2) ? 0 : cur + 1;
        sb = (sb == 2) ? 0 : sb + 1;
    }

    int nl = lr;
    float dv = dinv_s[nl];
    if (MODE == 1) {                              // final: relu, f32, node-major
#pragma unroll
        for (int rb = 0; rb < 2; rb++) {
            int f0 = w * 32 + rb * 16 + lg * 4;
            float v[4];
#pragma unroll
            for (int r = 0; r < 4; r++) {
                float idv = bf2f(Ttb[(size_t)(f0 + r) * NN + n0 + nl]);
                v[r] = fmaxf((acc[rb][r] + idv) * dv, 0.f);
            }
            *(float4*)&HsF[((size_t)b * NN + n0 + nl) * DD + f0] = make_float4(v[0], v[1], v[2], v[3]);
        }
        return;
    }
    // MODE 0: H -> LDS (reuse T_s buffer 0; all pipeline reads done), then @ WtN
    unsigned short* H_s = T_s;                    // [16][128] swizzled, row stride 256B
#pragma unroll
    for (int rb = 0; rb < 2; rb++) {
        int f0 = w * 32 + rb * 16 + lg * 4;
        us4 o;
#pragma unroll
        for (int r = 0; r < 4; r++) {
            float idv = bf2f(Ttb[(size_t)(f0 + r) * NN + n0 + nl]);
            o[r] = f2bf((acc[rb][r] + idv) * dv);
        }
        int byt = (nl * 256 + f0 * 2) ^ ((nl & 7) << 4);
        *(us4*)((char*)H_s + byt) = o;
    }
    __syncthreads();
    ffrag acc2[2] = {};
#pragma unroll
    for (int ks = 0; ks < 4; ks++) {
        int k0 = ks * 32 + lg * 8;
        bfrag a2[2], b2;
#pragma unroll
        for (int rb = 0; rb < 2; rb++) {
            int row = w * 32 + rb * 16 + lr;
            int byt = (row * 256 + k0 * 2) ^ ((row & 7) << 4);
            a2[rb] = *(const bfrag*)((const char*)W_s + byt);
        }
        {
            int row = lr;
            int byt = (row * 256 + k0 * 2) ^ ((row & 7) << 4);
            b2 = *(const bfrag*)((const char*)H_s + byt);
        }
#pragma unroll
        for (int rb = 0; rb < 2; rb++)
            acc2[rb] = __builtin_amdgcn_mfma_f32_16x16x32_bf16(a2[rb], b2, acc2[rb], 0, 0, 0);
    }
    unsigned short* TtNb = TtN + (size_t)b * DD * NN;
#pragma unroll
    for (int rb = 0; rb < 2; rb++)
#pragma unroll
        for (int r = 0; r < 4; r++) {
            int f2 = w * 32 + rb * 16 + lg * 4 + r;
            TtNb[(size_t)f2 * NN + n0 + nl] = f2bf(acc2[rb][r] * dv);
        }
}

// ---------------------------------------------------------------- launcher
extern "C" void kernel_launch(void* const* d_in, const int* in_sizes, int n_in,
                              void* d_out, int out_size, void* d_ws, size_t ws_size,
                              hipStream_t stream) {
    const float* X      = (const float*)d_in[0];
    const float* a_link = (const float*)d_in[1];
    const float* W0     = (const float*)d_in[2];
    const float* W1     = (const float*)d_in[3];
    const float* W2     = (const float*)d_in[4];
    float* out = (float*)d_out;

    const size_t HND = (size_t)BB * NN * DD;     // 524288
    const size_t HNN = (size_t)BB * NN * NN;     // 4194304
    float* Hs = out;
    float* As = out + HND;
    float* Xo = out + HND + HNN;
    float* Ds = out + 2 * HND + HNN;

    // scratch layout (bytes): Abf 8388608 | Xbf 1048576 | TtA 1048576 | TtB 1048576
    //                         | Wt 98304 | Pp 262144  => total 11894784
    const size_t NEED = 11894784;
    bool usews = (ws_size >= NEED);
    char* scr = usews ? (char*)d_ws : (char*)Ds;

    unsigned short* Abf = (unsigned short*)(scr);
    unsigned short* Xbf = (unsigned short*)(scr + 8388608);
    unsigned short* TtA = (unsigned short*)(scr + 9437184);
    unsigned short* TtB = (unsigned short*)(scr + 10485760);
    unsigned short* Wt  = (unsigned short*)(scr + 11534336);
    float* Pp           = (float*)(scr + 11632640);

    adj_kernel<<<dim3(16, 16, usews ? 6 : 5), 256, 0, stream>>>(
        X, a_link, W0, W1, W2, As, Abf, Xbf, Wt, Pp, Xo, usews ? Ds : nullptr);

    gw0_kernel<<<dim3(64, BB), 256, 0, stream>>>(Xbf, Wt, Pp, TtA);
    ga_kernel<0><<<dim3(64, BB), 256, 0, stream>>>(Abf, TtA, Wt + 16384, Pp, TtB, nullptr);
    ga_kernel<0><<<dim3(64, BB), 256, 0, stream>>>(Abf, TtB, Wt + 32768, Pp, TtA, nullptr);
    ga_kernel<1><<<dim3(64, BB), 256, 0, stream>>>(Abf, TtA, nullptr, Pp, nullptr, Hs);

    if (!usews)                                   // scratch lived in Ds: zero it now
        zero_f4<<<dim3(4096), 256, 0, stream>>>((float4*)Ds, (int)(HNN / 4));
}